// Round 3
// baseline (911.658 us; speedup 1.0000x reference)
//
#include <hip/hip_runtime.h>

#define TPB 256
#define HWSZ 9216      // 96*96

typedef __attribute__((ext_vector_type(8))) short short8x;
typedef __attribute__((ext_vector_type(4))) float f32x4;
typedef unsigned short ushort_t;
typedef unsigned int uint_t;

__device__ __forceinline__ float sigf(float v) { return 1.0f / (1.0f + __expf(-v)); }

__device__ __forceinline__ ushort_t f2bf(float f) {
  uint_t u = __float_as_uint(f);
  u = (u + 0x7fffu + ((u >> 16) & 1u)) >> 16;
  return (ushort_t)u;
}
__device__ __forceinline__ float bf2f(ushort_t h) {
  return __uint_as_float(((uint_t)h) << 16);
}

// fp32 epilogue-LDS swizzle (1024B rows): bijective, conflict-free columns
__device__ __forceinline__ int swz32(int p, int c) {
  return p * 1024 + ((((c * 4) ^ ((p & 7) << 4)) ^ (((p >> 3) & 3) << 2)));
}

// async global->LDS: one 16KB fragment-major slice (1024 uint4), 6 waves
__device__ __forceinline__ void stage_slice(const uint4* __restrict__ src,
                                            char* ldsbase, int tid) {
  int lane = tid & 63;
  int wv = tid >> 6;
  for (int c = wv; c < 16; c += 6) {
    __builtin_amdgcn_global_load_lds(
        (const __attribute__((address_space(1))) unsigned int*)(src + c * 64 + lane),
        (__attribute__((address_space(3))) unsigned int*)(ldsbase + c * 1024),
        16, 0, 0);
  }
}

// ---------------- pack weights to fragment-major bf16 ----------------
// B-frag tile(kt,nt): elem(l,j) = B[kt*32+(l>>4)*8+j][nt*16+(l&15)], 1KB each
// Gp:  [dir4][kt8][nt16][64][8]           (gate weights, B[k][dd]=g[dd][k])
// Ftp: [kt8][nt16][64][8]                 (fuse)
// W1p: [jc4][kt8][nt16][64][8]            nt<8: a-cols jc*128+nt*16+.., nt>=8: g-cols 512+...
// W2p: [kt16][nt16][64][8]
__global__ __launch_bounds__(TPB) void k_pack(
    const float* __restrict__ lrg, const float* __restrict__ rlg,
    const float* __restrict__ tbg, const float* __restrict__ btg,
    const float* __restrict__ fusew, const float* __restrict__ ff1w,
    const float* __restrict__ ff2w,
    ushort_t* __restrict__ Gp, ushort_t* __restrict__ Ftp,
    ushort_t* __restrict__ W1p, ushort_t* __restrict__ W2p) {
  int i = blockIdx.x * TPB + threadIdx.x;
  if (i < 262144) {
    int d = i >> 16, r = i & 65535;
    int kt = r >> 13, nt = (r >> 9) & 15, l = (r >> 3) & 63, j = r & 7;
    int k = kt * 32 + (l >> 4) * 8 + j;
    int n_ = nt * 16 + (l & 15);
    const float* g = (d == 0) ? lrg : (d == 1) ? rlg : (d == 2) ? tbg : btg;
    Gp[i] = f2bf(g[n_ * 256 + k]);
  } else if (i < 327680) {
    int r = i - 262144;
    int kt = r >> 13, nt = (r >> 9) & 15, l = (r >> 3) & 63, j = r & 7;
    int k = kt * 32 + (l >> 4) * 8 + j;
    int n_ = nt * 16 + (l & 15);
    Ftp[r] = f2bf(fusew[n_ * 256 + k]);
  } else if (i < 589824) {
    int r = i - 327680;
    int jc = r >> 16, kt = (r >> 13) & 7, nt = (r >> 9) & 15, l = (r >> 3) & 63, j = r & 7;
    int k = kt * 32 + (l >> 4) * 8 + j;
    int col = (nt < 8) ? (jc * 128 + nt * 16 + (l & 15))
                       : (512 + jc * 128 + (nt - 8) * 16 + (l & 15));
    W1p[r] = f2bf(ff1w[col * 256 + k]);
  } else if (i < 720896) {
    int r = i - 589824;
    int kt = r >> 13, nt = (r >> 9) & 15, l = (r >> 3) & 63, j = r & 7;
    int k = kt * 32 + (l >> 4) * 8 + j;
    int n_ = nt * 16 + (l & 15);
    W2p[r] = f2bf(ff2w[n_ * 512 + k]);
  }
}

// ---------------- per-(n,c) LayerNorm2d stats ----------------
__global__ __launch_bounds__(TPB) void k_stats(const float* __restrict__ src,
                                               float* __restrict__ mean,
                                               float* __restrict__ rstd) {
  int nc = blockIdx.x;
  const float* p = src + (long)nc * HWSZ;
  float s = 0.f, s2 = 0.f;
  for (int i = threadIdx.x; i < HWSZ; i += TPB) {
    float v = p[i];
    s += v;
    s2 = fmaf(v, v, s2);
  }
#pragma unroll
  for (int off = 32; off > 0; off >>= 1) {
    s += __shfl_down(s, off);
    s2 += __shfl_down(s2, off);
  }
  __shared__ float ls[4], ls2[4];
  int lane = threadIdx.x & 63, wv = threadIdx.x >> 6;
  if (lane == 0) { ls[wv] = s; ls2[wv] = s2; }
  __syncthreads();
  if (threadIdx.x == 0) {
    float S = ls[0] + ls[1] + ls[2] + ls[3];
    float S2 = ls2[0] + ls2[1] + ls2[2] + ls2[3];
    float m = S * (1.0f / HWSZ);
    float var = S2 * (1.0f / HWSZ) - m * m;
    mean[nc] = m;
    rstd[nc] = rsqrtf(fmaxf(var, 0.f) + 1e-6f);
  }
}

// ---------------- ln1 + depthwise 3x3 -> y (NHWC bf16) ----------------
__global__ __launch_bounds__(TPB) void k_lndw(
    const float* __restrict__ x, const float* __restrict__ mean1,
    const float* __restrict__ rstd1, const float* __restrict__ ln1w,
    const float* __restrict__ ln1b, const float* __restrict__ dww,
    const float* __restrict__ dwb, ushort_t* __restrict__ y) {
  __shared__ float xl[3][32][101];
  int tid = threadIdx.x;
  int bid = blockIdx.x;
  int cb = (bid & 7) * 32;
  int h = (bid >> 3) % 96;
  int n = bid / 768;

  if (tid < 192) {
    int col = (tid & 1) ? 97 : 0;
    int rc = tid >> 1;
    xl[rc >> 5][rc & 31][col] = 0.f;
  }
  for (int i = tid; i < 3 * 32 * 96; i += TPB) {
    int w = i % 96;
    int rc = i / 96;
    int cc = rc & 31, rr = rc >> 5;
    int hh = h + rr - 1;
    float v = 0.f;
    if (hh >= 0 && hh < 96) {
      int c = cb + cc;
      int nc = n * 256 + c;
      float xv = x[(long)nc * HWSZ + hh * 96 + w];
      v = (xv - mean1[nc]) * rstd1[nc] * ln1w[c] + ln1b[c];
    }
    xl[rr][cc][w + 1] = v;
  }
  __syncthreads();

  int cc = tid & 31, wg = tid >> 5;
  int c = cb + cc;
  float wgt[9];
#pragma unroll
  for (int t = 0; t < 9; ++t) wgt[t] = dww[t * 256 + c];
  float bias = dwb[c];
  for (int wi = 0; wi < 12; ++wi) {
    int w = wg * 12 + wi;
    float acc = bias;
#pragma unroll
    for (int kh = 0; kh < 3; ++kh)
#pragma unroll
      for (int kw = 0; kw < 3; ++kw)
        acc = fmaf(xl[kh][cc][w + kw], wgt[kh * 3 + kw], acc);
    y[((long)(n * 96 + h) * 96 + w) * 256 + c] = f2bf(acc);
  }
}

// ---------------- scan pair (MFMA): gate GEMM + dwconv1d*sigmoid ----------------
// Block = one full line (96 pixels). 6 waves x (M=16, N=256).
template <int VERT>
__global__ __launch_bounds__(384) void k_scan(
    const ushort_t* __restrict__ y, const ushort_t* __restrict__ Gp,
    const float* __restrict__ dwaw, const float* __restrict__ dwab,
    const float* __restrict__ gab, const float* __restrict__ dwbw,
    const float* __restrict__ dwbb, const float* __restrict__ gbb,
    ushort_t* __restrict__ o) {
  __shared__ __align__(16) char pool[133120];
  char* ylds = pool;            // 100 rows x 512B (pixel q at row q+2), swizzled
  char* bst  = pool + 51200;    // 2 x 16KB slice double-buffer (linear)
  char* olds = pool + 83968;    // 96 rows x 512B bf16, swizzled

  int tid = threadIdx.x;
  int bid = blockIdx.x;
  int line = bid % 96, n = bid / 96;

  for (int u = tid; u < 3200; u += 384) {
    int r = u >> 5, ks = u & 31;
    int q = r - 2;
    uint4 v = make_uint4(0, 0, 0, 0);
    if (q >= 0 && q < 96) {
      long pix = VERT ? ((long)(n * 96 + q) * 96 + line)
                      : ((long)(n * 96 + line) * 96 + q);
      v = *(const uint4*)(y + pix * 256 + ks * 8);
    }
    *(uint4*)(ylds + r * 512 + ((ks * 16) ^ ((r & 7) << 4))) = v;
  }

  int l = tid & 63, wr = tid >> 6;
  int llo = l & 15, lhi = l >> 4;
  int arow = 2 + wr * 16 + llo;

  const uint4* gp4 = (const uint4*)Gp + (long)VERT * 16384;
  stage_slice(gp4, bst, tid);
  __syncthreads();   // drains slice 0 + ylds visible

  f32x4 acc[16];
  for (int s = 0; s < 16; ++s) {
    int dir = s >> 3, kt = s & 7;
    if ((s & 7) == 0) {
#pragma unroll
      for (int nt = 0; nt < 16; ++nt) acc[nt] = (f32x4){0.f, 0.f, 0.f, 0.f};
    }
    if (s + 1 < 16)
      stage_slice(gp4 + (long)(s + 1) * 1024, bst + ((s + 1) & 1) * 16384, tid);
    const char* cur = bst + (s & 1) * 16384;
    short8x a = *(const short8x*)(ylds + arow * 512 +
                                  ((kt * 64 + lhi * 16) ^ ((arow & 7) << 4)));
#pragma unroll
    for (int nt = 0; nt < 16; ++nt) {
      short8x b = *(const short8x*)(cur + (nt * 64 + l) * 16);
      acc[nt] = __builtin_amdgcn_mfma_f32_16x16x32_bf16(a, b, acc[nt], 0, 0, 0);
    }
    if (kt == 7) {
      // epilogue for this direction: conv5 (reversed for dir1) * sigmoid(gate)
      const float* dwv = dir ? dwbw : dwaw;
      const float* dbv = dir ? dwbb : dwab;
      const float* gbv = dir ? gbb : gab;
      int pbase = wr * 16 + lhi * 4;
#pragma unroll
      for (int nt = 0; nt < 16; ++nt) {
        int c = nt * 16 + llo;
        float wt[5];
#pragma unroll
        for (int t = 0; t < 5; ++t)
          wt[t] = dir ? dwv[(4 - t) * 256 + c] : dwv[t * 256 + c];
        float cb = dbv[c], gb = gbv[c];
        float yv[8];
#pragma unroll
        for (int t = 0; t < 8; ++t) {
          int ry = pbase + t;
          yv[t] = bf2f(*(const ushort_t*)(ylds + ry * 512 +
                                          ((c * 2) ^ ((ry & 7) << 4))));
        }
#pragma unroll
        for (int r = 0; r < 4; ++r) {
          float conv = cb;
#pragma unroll
          for (int t = 0; t < 5; ++t) conv = fmaf(yv[r + t], wt[t], conv);
          float val = conv * sigf(acc[nt][r] + gb);
          int p = pbase + r;
          ushort_t* op = (ushort_t*)(olds + p * 512 + ((c * 2) ^ ((p & 7) << 4)));
          if (dir == 0) *op = f2bf(val);
          else          *op = f2bf(bf2f(*op) + val);
        }
      }
    }
    __syncthreads();
  }

  for (int u = tid; u < 3072; u += 384) {
    int p = u >> 5, ks = u & 31;
    uint4 v = *(const uint4*)(olds + p * 512 + ((ks * 16) ^ ((p & 7) << 4)));
    long pix = VERT ? ((long)(n * 96 + p) * 96 + line)
                    : ((long)(n * 96 + line) * 96 + p);
    ushort_t* dst = o + pix * 256 + ks * 8;
    if (VERT) {
      uint4 old = *(uint4*)dst;
      ushort_t* a8 = (ushort_t*)&v;
      ushort_t* b8 = (ushort_t*)&old;
#pragma unroll
      for (int j = 0; j < 8; ++j) a8[j] = f2bf(bf2f(a8[j]) + bf2f(b8[j]));
      *(uint4*)dst = v;
    } else {
      *(uint4*)dst = v;
    }
  }
}

// ---------------- fuse GEMM + residual: out(NCHW) = x + o@Ft + b ----------------
__global__ __launch_bounds__(384) void k_fuse(
    const ushort_t* __restrict__ o, const ushort_t* __restrict__ Ftp,
    const float* __restrict__ fuseb, const float* __restrict__ x,
    float* __restrict__ out) {
  __shared__ __align__(16) char pool[81920];
  char* alds = pool;            // 96 x 512B bf16, swizzled; reused as f32 epilogue
  char* bst  = pool + 49152;    // 2 x 16KB

  int tid = threadIdx.x;
  int pix0 = blockIdx.x * 96;
  int n = pix0 / HWSZ, hw0 = pix0 % HWSZ;

  for (int u = tid; u < 3072; u += 384) {
    int r = u >> 5, ks = u & 31;
    uint4 v = *(const uint4*)(o + (long)(pix0 + r) * 256 + ks * 8);
    *(uint4*)(alds + r * 512 + ((ks * 16) ^ ((r & 7) << 4))) = v;
  }

  int l = tid & 63, wr = tid >> 6;
  int llo = l & 15, lhi = l >> 4;
  int arow = wr * 16 + llo;

  const uint4* fp4 = (const uint4*)Ftp;
  stage_slice(fp4, bst, tid);
  __syncthreads();

  f32x4 acc[16];
#pragma unroll
  for (int nt = 0; nt < 16; ++nt) acc[nt] = (f32x4){0.f, 0.f, 0.f, 0.f};

  for (int s = 0; s < 8; ++s) {
    if (s + 1 < 8)
      stage_slice(fp4 + (s + 1) * 1024, bst + ((s + 1) & 1) * 16384, tid);
    const char* cur = bst + (s & 1) * 16384;
    short8x a = *(const short8x*)(alds + arow * 512 +
                                  ((s * 64 + lhi * 16) ^ ((arow & 7) << 4)));
#pragma unroll
    for (int nt = 0; nt < 16; ++nt) {
      short8x b = *(const short8x*)(cur + (nt * 64 + l) * 16);
      acc[nt] = __builtin_amdgcn_mfma_f32_16x16x32_bf16(a, b, acc[nt], 0, 0, 0);
    }
    __syncthreads();
  }

  // epilogue: 2 chunks of 48 rows reusing alds as fp32
  for (int q = 0; q < 2; ++q) {
    if (wr >= q * 3 && wr < q * 3 + 3) {
#pragma unroll
      for (int nt = 0; nt < 16; ++nt) {
        int c = nt * 16 + llo;
        float fb = fuseb[c];
#pragma unroll
        for (int r = 0; r < 4; ++r) {
          int p = (wr - q * 3) * 16 + lhi * 4 + r;
          *(float*)(alds + swz32(p, c)) = acc[nt][r] + fb;
        }
      }
    }
    __syncthreads();
    for (int i = tid; i < 12288; i += 384) {
      int c = i / 48, p = i % 48;
      long addr = (long)(n * 256 + c) * HWSZ + hw0 + q * 48 + p;
      out[addr] = x[addr] + *(const float*)(alds + swz32(p, c));
    }
    __syncthreads();
  }
}

// ---------------- ln2 + ff1 + GLU + ff2 + residual (out +=) ----------------
__global__ __launch_bounds__(384) void k_ff(
    const float* __restrict__ xres, const float* __restrict__ mean2,
    const float* __restrict__ rstd2, const float* __restrict__ ln2w,
    const float* __restrict__ ln2b, const ushort_t* __restrict__ W1p,
    const float* __restrict__ ff1b, const ushort_t* __restrict__ W2p,
    const float* __restrict__ ff2b, float* __restrict__ out) {
  __shared__ __align__(16) char pool[106496];
  char* hA  = pool;             // 96 x 512B bf16, swizzled
  char* uA  = pool + 49152;     // 96 x 256B bf16, swizzled
  char* bst = pool + 73728;     // 2 x 16KB; reused as fp32 epilogue (32 rows)

  int tid = threadIdx.x;
  int pix0 = blockIdx.x * 96;
  int n = pix0 / HWSZ, hw0 = pix0 % HWSZ;

  for (int i = tid; i < 24576; i += 384) {
    int c = i / 96, p = i % 96;
    int nc = n * 256 + c;
    float v = xres[(long)nc * HWSZ + hw0 + p];
    float hv = (v - mean2[nc]) * rstd2[nc] * ln2w[c] + ln2b[c];
    *(ushort_t*)(hA + p * 512 + ((c * 2) ^ ((p & 7) << 4))) = f2bf(hv);
  }

  int l = tid & 63, wr = tid >> 6;
  int llo = l & 15, lhi = l >> 4;
  int arow = wr * 16 + llo;

  const uint4* W1p4 = (const uint4*)W1p;
  const uint4* W2p4 = (const uint4*)W2p;

  stage_slice(W1p4, bst, tid);
  __syncthreads();   // drains slice 0 + hA visible

  f32x4 zacc[16];
#pragma unroll
  for (int nt = 0; nt < 16; ++nt) zacc[nt] = (f32x4){0.f, 0.f, 0.f, 0.f};
  f32x4 tacc[16];

  for (int s = 0; s < 48; ++s) {
    int jc = s / 12, ph = s % 12;
    if (s + 1 < 48) {
      int jc1 = (s + 1) / 12, ph1 = (s + 1) % 12;
      const uint4* nsrc = (ph1 < 8) ? (W1p4 + jc1 * 8192 + ph1 * 1024)
                                    : (W2p4 + (jc1 * 4 + ph1 - 8) * 1024);
      stage_slice(nsrc, bst + ((s + 1) & 1) * 16384, tid);
    }
    const char* cur = bst + (s & 1) * 16384;
    if (ph == 0) {
#pragma unroll
      for (int nt = 0; nt < 16; ++nt) tacc[nt] = (f32x4){0.f, 0.f, 0.f, 0.f};
    }
    if (ph < 8) {
      short8x a = *(const short8x*)(hA + arow * 512 +
                                    ((ph * 64 + lhi * 16) ^ ((arow & 7) << 4)));
#pragma unroll
      for (int nt = 0; nt < 16; ++nt) {
        short8x b = *(const short8x*)(cur + (nt * 64 + l) * 16);
        tacc[nt] = __builtin_amdgcn_mfma_f32_16x16x32_bf16(a, b, tacc[nt], 0, 0, 0);
      }
      if (ph == 7) {
        // GLU in-register -> uA
#pragma unroll
        for (int ntq = 0; ntq < 8; ++ntq) {
          int colg = jc * 128 + ntq * 16 + llo;
          float ba = ff1b[colg], bg = ff1b[512 + colg];
#pragma unroll
          for (int r = 0; r < 4; ++r) {
            float av = tacc[ntq][r] + ba;
            float gv = tacc[ntq + 8][r] + bg;
            int p = wr * 16 + lhi * 4 + r;
            int cu = ntq * 16 + llo;
            *(ushort_t*)(uA + p * 256 + ((cu * 2) ^ ((p & 7) << 4))) =
                f2bf(av * sigf(gv));
          }
        }
      }
    } else {
      int kt2 = ph - 8;
      short8x a2 = *(const short8x*)(uA + arow * 256 +
                                     ((kt2 * 64 + lhi * 16) ^ ((arow & 7) << 4)));
#pragma unroll
      for (int nt = 0; nt < 16; ++nt) {
        short8x b = *(const short8x*)(cur + (nt * 64 + l) * 16);
        zacc[nt] = __builtin_amdgcn_mfma_f32_16x16x32_bf16(a2, b, zacc[nt], 0, 0, 0);
      }
    }
    __syncthreads();
  }

  // epilogue: 3 chunks of 32 rows, reuse bst as fp32 buffer
  for (int q = 0; q < 3; ++q) {
    if ((wr >> 1) == q) {
#pragma unroll
      for (int nt = 0; nt < 16; ++nt) {
        int c = nt * 16 + llo;
        float fb = ff2b[c];
#pragma unroll
        for (int r = 0; r < 4; ++r) {
          int p = (wr & 1) * 16 + lhi * 4 + r;
          *(float*)(bst + swz32(p, c)) = zacc[nt][r] + fb;
        }
      }
    }
    __syncthreads();
    for (int i = tid; i < 8192; i += 384) {
      int c = i >> 5, p = i & 31;
      long addr = (long)(n * 256 + c) * HWSZ + hw0 + q * 32 + p;
      out[addr] += *(const float*)(bst + swz32(p, c));
    }
    __syncthreads();
  }
}

extern "C" void kernel_launch(void* const* d_in, const int* in_sizes, int n_in,
                              void* d_out, int out_size, void* d_ws, size_t ws_size,
                              hipStream_t stream) {
  (void)in_sizes; (void)n_in; (void)out_size; (void)ws_size;
  const float* x     = (const float*)d_in[0];
  const float* ln1w  = (const float*)d_in[1];
  const float* ln1b  = (const float*)d_in[2];
  const float* dww   = (const float*)d_in[3];
  const float* dwb   = (const float*)d_in[4];
  const float* lr_w  = (const float*)d_in[5];
  const float* lr_b  = (const float*)d_in[6];
  const float* lr_gw = (const float*)d_in[7];
  const float* lr_gb = (const float*)d_in[8];
  const float* rl_w  = (const float*)d_in[9];
  const float* rl_b  = (const float*)d_in[10];
  const float* rl_gw = (const float*)d_in[11];
  const float* rl_gb = (const float*)d_in[12];
  const float* tb_w  = (const float*)d_in[13];
  const float* tb_b  = (const float*)d_in[14];
  const float* tb_gw = (const float*)d_in[15];
  const float* tb_gb = (const float*)d_in[16];
  const float* bt_w  = (const float*)d_in[17];
  const float* bt_b  = (const float*)d_in[18];
  const float* bt_gw = (const float*)d_in[19];
  const float* bt_gb = (const float*)d_in[20];
  const float* fusew = (const float*)d_in[21];
  const float* fuseb = (const float*)d_in[22];
  const float* ln2w  = (const float*)d_in[23];
  const float* ln2b  = (const float*)d_in[24];
  const float* ff1w  = (const float*)d_in[25];
  const float* ff1b  = (const float*)d_in[26];
  const float* ff2w  = (const float*)d_in[27];
  const float* ff2b  = (const float*)d_in[28];

  float* out = (float*)d_out;
  ushort_t* y = (ushort_t*)d_ws;                  // 18874368 bf16
  ushort_t* o = y + 18874368;                     // 18874368 bf16
  float* mean1 = (float*)(o + 18874368);
  float* rstd1 = mean1 + 2048;
  float* mean2 = rstd1 + 2048;
  float* rstd2 = mean2 + 2048;
  ushort_t* Gp  = (ushort_t*)(rstd2 + 2048);      // 262144
  ushort_t* Ftp = Gp + 262144;                    // 65536
  ushort_t* W1p = Ftp + 65536;                    // 262144
  ushort_t* W2p = W1p + 262144;                   // 131072

  k_pack<<<2816, TPB, 0, stream>>>(lr_gw, rl_gw, tb_gw, bt_gw, fusew, ff1w, ff2w,
                                   Gp, Ftp, W1p, W2p);
  k_stats<<<2048, TPB, 0, stream>>>(x, mean1, rstd1);
  k_lndw<<<6144, TPB, 0, stream>>>(x, mean1, rstd1, ln1w, ln1b, dww, dwb, y);
  k_scan<0><<<768, 384, 0, stream>>>(y, Gp, lr_w, lr_b, lr_gb, rl_w, rl_b, rl_gb, o);
  k_scan<1><<<768, 384, 0, stream>>>(y, Gp, tb_w, tb_b, tb_gb, bt_w, bt_b, bt_gb, o);
  k_fuse<<<768, 384, 0, stream>>>(o, Ftp, fuseb, x, out);
  k_stats<<<2048, TPB, 0, stream>>>(out, mean2, rstd2);
  k_ff<<<768, 384, 0, stream>>>(out, mean2, rstd2, ln2w, ln2b, W1p, ff1b,
                                W2p, ff2b, out);
}

// Round 4
// 633.243 us; speedup vs baseline: 1.4397x; 1.4397x over previous
//
#include <hip/hip_runtime.h>

#define TPB 256
#define HWSZ 9216      // 96*96

typedef __attribute__((ext_vector_type(8))) short short8x;
typedef __attribute__((ext_vector_type(4))) float f32x4;
typedef unsigned short ushort_t;
typedef unsigned int uint_t;

__device__ __forceinline__ float sigf(float v) { return 1.0f / (1.0f + __expf(-v)); }

__device__ __forceinline__ ushort_t f2bf(float f) {
  uint_t u = __float_as_uint(f);
  u = (u + 0x7fffu + ((u >> 16) & 1u)) >> 16;
  return (ushort_t)u;
}
__device__ __forceinline__ float bf2f(ushort_t h) {
  return __uint_as_float(((uint_t)h) << 16);
}

// fp32 epilogue-LDS swizzle (1024B rows): bijective, conflict-free columns
__device__ __forceinline__ int swz32(int p, int c) {
  return p * 1024 + ((((c * 4) ^ ((p & 7) << 4)) ^ (((p >> 3) & 3) << 2)));
}

// ---------------- pack weights to fragment-major bf16 ----------------
// B-frag tile(kt,nt): elem(l,j) = B[kt*32+(l>>4)*8+j][col(nt,l&15)], 1KB each
// Gp:  [dir4][kt8][nt16][64][8]
// Ftp: [kt8][nt16][64][8]
// W1p: [jc4][kt8][nt16][64][8], nt even: a-col jc*128+(nt>>1)*16+llo,
//                               nt odd : g-col 512+jc*128+(nt>>1)*16+llo
// W2p: [kt16][nt16][64][8]
__global__ __launch_bounds__(TPB) void k_pack(
    const float* __restrict__ lrg, const float* __restrict__ rlg,
    const float* __restrict__ tbg, const float* __restrict__ btg,
    const float* __restrict__ fusew, const float* __restrict__ ff1w,
    const float* __restrict__ ff2w,
    ushort_t* __restrict__ Gp, ushort_t* __restrict__ Ftp,
    ushort_t* __restrict__ W1p, ushort_t* __restrict__ W2p) {
  int i = blockIdx.x * TPB + threadIdx.x;
  if (i < 262144) {
    int d = i >> 16, r = i & 65535;
    int kt = r >> 13, nt = (r >> 9) & 15, l = (r >> 3) & 63, j = r & 7;
    int k = kt * 32 + (l >> 4) * 8 + j;
    int n_ = nt * 16 + (l & 15);
    const float* g = (d == 0) ? lrg : (d == 1) ? rlg : (d == 2) ? tbg : btg;
    Gp[i] = f2bf(g[n_ * 256 + k]);
  } else if (i < 327680) {
    int r = i - 262144;
    int kt = r >> 13, nt = (r >> 9) & 15, l = (r >> 3) & 63, j = r & 7;
    int k = kt * 32 + (l >> 4) * 8 + j;
    int n_ = nt * 16 + (l & 15);
    Ftp[r] = f2bf(fusew[n_ * 256 + k]);
  } else if (i < 589824) {
    int r = i - 327680;
    int jc = r >> 16, kt = (r >> 13) & 7, nt = (r >> 9) & 15, l = (r >> 3) & 63, j = r & 7;
    int k = kt * 32 + (l >> 4) * 8 + j;
    int base = jc * 128 + (nt >> 1) * 16 + (l & 15);
    int col = (nt & 1) ? (512 + base) : base;
    W1p[r] = f2bf(ff1w[col * 256 + k]);
  } else if (i < 720896) {
    int r = i - 589824;
    int kt = r >> 13, nt = (r >> 9) & 15, l = (r >> 3) & 63, j = r & 7;
    int k = kt * 32 + (l >> 4) * 8 + j;
    int n_ = nt * 16 + (l & 15);
    W2p[r] = f2bf(ff2w[n_ * 512 + k]);
  }
}

// ---------------- per-(n,c) LayerNorm2d stats ----------------
__global__ __launch_bounds__(TPB) void k_stats(const float* __restrict__ src,
                                               float* __restrict__ mean,
                                               float* __restrict__ rstd) {
  int nc = blockIdx.x;
  const float* p = src + (long)nc * HWSZ;
  float s = 0.f, s2 = 0.f;
  for (int i = threadIdx.x; i < HWSZ; i += TPB) {
    float v = p[i];
    s += v;
    s2 = fmaf(v, v, s2);
  }
#pragma unroll
  for (int off = 32; off > 0; off >>= 1) {
    s += __shfl_down(s, off);
    s2 += __shfl_down(s2, off);
  }
  __shared__ float ls[4], ls2[4];
  int lane = threadIdx.x & 63, wv = threadIdx.x >> 6;
  if (lane == 0) { ls[wv] = s; ls2[wv] = s2; }
  __syncthreads();
  if (threadIdx.x == 0) {
    float S = ls[0] + ls[1] + ls[2] + ls[3];
    float S2 = ls2[0] + ls2[1] + ls2[2] + ls2[3];
    float m = S * (1.0f / HWSZ);
    float var = S2 * (1.0f / HWSZ) - m * m;
    mean[nc] = m;
    rstd[nc] = rsqrtf(fmaxf(var, 0.f) + 1e-6f);
  }
}

// ---------------- ln1 + depthwise 3x3 -> y (NHWC bf16) ----------------
__global__ __launch_bounds__(TPB) void k_lndw(
    const float* __restrict__ x, const float* __restrict__ mean1,
    const float* __restrict__ rstd1, const float* __restrict__ ln1w,
    const float* __restrict__ ln1b, const float* __restrict__ dww,
    const float* __restrict__ dwb, ushort_t* __restrict__ y) {
  __shared__ float xl[3][32][101];
  int tid = threadIdx.x;
  int bid = blockIdx.x;
  int cb = (bid & 7) * 32;
  int h = (bid >> 3) % 96;
  int n = bid / 768;

  if (tid < 192) {
    int col = (tid & 1) ? 97 : 0;
    int rc = tid >> 1;
    xl[rc >> 5][rc & 31][col] = 0.f;
  }
  for (int i = tid; i < 3 * 32 * 96; i += TPB) {
    int w = i % 96;
    int rc = i / 96;
    int cc = rc & 31, rr = rc >> 5;
    int hh = h + rr - 1;
    float v = 0.f;
    if (hh >= 0 && hh < 96) {
      int c = cb + cc;
      int nc = n * 256 + c;
      float xv = x[(long)nc * HWSZ + hh * 96 + w];
      v = (xv - mean1[nc]) * rstd1[nc] * ln1w[c] + ln1b[c];
    }
    xl[rr][cc][w + 1] = v;
  }
  __syncthreads();

  int cc = tid & 31, wg = tid >> 5;
  int c = cb + cc;
  float wgt[9];
#pragma unroll
  for (int t = 0; t < 9; ++t) wgt[t] = dww[t * 256 + c];
  float bias = dwb[c];
  for (int wi = 0; wi < 12; ++wi) {
    int w = wg * 12 + wi;
    float acc = bias;
#pragma unroll
    for (int kh = 0; kh < 3; ++kh)
#pragma unroll
      for (int kw = 0; kw < 3; ++kw)
        acc = fmaf(xl[kh][cc][w + kw], wgt[kh * 3 + kw], acc);
    y[((long)(n * 96 + h) * 96 + w) * 256 + c] = f2bf(acc);
  }
}

// ---------------- scan pair: gate GEMM (B from L2) + dwconv1d*sigmoid --------
// Block = 32-pixel segment. 4 waves, wave w owns nt w*4..w*4+3 (64 cols).
template <int VERT>
__global__ __launch_bounds__(TPB, 3) void k_scan(
    const ushort_t* __restrict__ y, const ushort_t* __restrict__ Gp,
    const float* __restrict__ dwaw, const float* __restrict__ dwab,
    const float* __restrict__ gab, const float* __restrict__ dwbw,
    const float* __restrict__ dwbb, const float* __restrict__ gbb,
    ushort_t* __restrict__ o) {
  __shared__ __align__(16) char pool[34816];
  char* ylds = pool;            // 36 rows x 512B, swizzled (pixel q at row q+2)
  char* olds = pool + 18432;    // 32 rows x 512B, swizzled

  int tid = threadIdx.x;
  int bid = blockIdx.x;
  int seg = bid % 3, line = (bid / 3) % 96, n = bid / 288;
  int p0 = seg * 32;

  for (int u = tid; u < 36 * 32; u += TPB) {
    int r = u >> 5, ks = u & 31;
    int q = p0 - 2 + r;
    uint4 v = make_uint4(0, 0, 0, 0);
    if (q >= 0 && q < 96) {
      long pix = VERT ? ((long)(n * 96 + q) * 96 + line)
                      : ((long)(n * 96 + line) * 96 + q);
      v = *(const uint4*)(y + pix * 256 + ks * 8);
    }
    *(uint4*)(ylds + r * 512 + ((ks * 16) ^ ((r & 7) << 4))) = v;
  }
  __syncthreads();

  int l = tid & 63, w = tid >> 6;
  int llo = l & 15, lhi = l >> 4;

  const uint4* gp4 = (const uint4*)Gp;
  float part[2][4][4];

#pragma unroll
  for (int diri = 0; diri < 2; ++diri) {
    int dir = VERT * 2 + diri;
    f32x4 acc[2][4];
#pragma unroll
    for (int mf = 0; mf < 2; ++mf)
#pragma unroll
      for (int ntl = 0; ntl < 4; ++ntl) acc[mf][ntl] = (f32x4){0.f, 0.f, 0.f, 0.f};

#pragma unroll
    for (int kt = 0; kt < 8; ++kt) {
      short8x a[2];
#pragma unroll
      for (int mf = 0; mf < 2; ++mf) {
        int arow = 2 + mf * 16 + llo;
        a[mf] = *(const short8x*)(ylds + arow * 512 +
                                  ((kt * 64 + lhi * 16) ^ ((arow & 7) << 4)));
      }
#pragma unroll
      for (int ntl = 0; ntl < 4; ++ntl) {
        short8x b = *(const short8x*)(gp4 + (long)(((dir * 8 + kt) * 16) +
                                                   w * 4 + ntl) * 64 + l);
#pragma unroll
        for (int mf = 0; mf < 2; ++mf)
          acc[mf][ntl] = __builtin_amdgcn_mfma_f32_16x16x32_bf16(a[mf], b,
                                                                 acc[mf][ntl], 0, 0, 0);
      }
    }

    const float* dwv = diri ? dwbw : dwaw;
    const float* dbv = diri ? dwbb : dwab;
    const float* gbv = diri ? gbb : gab;
#pragma unroll
    for (int ntl = 0; ntl < 4; ++ntl) {
      int c = w * 64 + ntl * 16 + llo;
      float wt[5];
#pragma unroll
      for (int t = 0; t < 5; ++t)
        wt[t] = diri ? dwv[(4 - t) * 256 + c] : dwv[t * 256 + c];
      float cb = dbv[c], gb = gbv[c];
#pragma unroll
      for (int mf = 0; mf < 2; ++mf) {
        int pbase = mf * 16 + lhi * 4;
        float yv[8];
#pragma unroll
        for (int t = 0; t < 8; ++t) {
          int ry = pbase + t;
          yv[t] = bf2f(*(const ushort_t*)(ylds + ry * 512 +
                                          ((c * 2) ^ ((ry & 7) << 4))));
        }
#pragma unroll
        for (int r = 0; r < 4; ++r) {
          float conv = cb;
#pragma unroll
          for (int t = 0; t < 5; ++t) conv = fmaf(yv[r + t], wt[t], conv);
          float val = conv * sigf(acc[mf][ntl][r] + gb);
          if (diri == 0) {
            part[mf][ntl][r] = val;
          } else {
            int p = pbase + r;
            *(ushort_t*)(olds + p * 512 + ((c * 2) ^ ((p & 7) << 4))) =
                f2bf(part[mf][ntl][r] + val);
          }
        }
      }
    }
  }
  __syncthreads();

  for (int u = tid; u < 32 * 32; u += TPB) {
    int p = u >> 5, ks = u & 31;
    uint4 v = *(const uint4*)(olds + p * 512 + ((ks * 16) ^ ((p & 7) << 4)));
    long pix = VERT ? ((long)(n * 96 + p0 + p) * 96 + line)
                    : ((long)(n * 96 + line) * 96 + p0 + p);
    ushort_t* dst = o + pix * 256 + ks * 8;
    if (VERT) {
      uint4 old = *(uint4*)dst;
      ushort_t* a8 = (ushort_t*)&v;
      ushort_t* b8 = (ushort_t*)&old;
#pragma unroll
      for (int j = 0; j < 8; ++j) a8[j] = f2bf(bf2f(a8[j]) + bf2f(b8[j]));
      *(uint4*)dst = v;
    } else {
      *(uint4*)dst = v;
    }
  }
}

// ---------------- fuse GEMM + residual: out(NCHW) = x + o@Ft + b ----------------
__global__ __launch_bounds__(TPB, 3) void k_fuse(
    const ushort_t* __restrict__ o, const ushort_t* __restrict__ Ftp,
    const float* __restrict__ fuseb, const float* __restrict__ x,
    float* __restrict__ out) {
  __shared__ __align__(16) char pool[49152];
  char* alds = pool;            // 32 x 512B bf16, swizzled
  char* eb   = pool + 16384;    // 32 x 1024B f32, swz32

  int tid = threadIdx.x;
  int pix0 = blockIdx.x * 32;
  int n = pix0 / HWSZ, hw0 = pix0 % HWSZ;

  for (int u = tid; u < 32 * 32; u += TPB) {
    int r = u >> 5, ks = u & 31;
    uint4 v = *(const uint4*)(o + (long)(pix0 + r) * 256 + ks * 8);
    *(uint4*)(alds + r * 512 + ((ks * 16) ^ ((r & 7) << 4))) = v;
  }
  __syncthreads();

  int l = tid & 63, w = tid >> 6;
  int llo = l & 15, lhi = l >> 4;

  const uint4* fp4 = (const uint4*)Ftp;
  f32x4 acc[2][4];
#pragma unroll
  for (int mf = 0; mf < 2; ++mf)
#pragma unroll
    for (int ntl = 0; ntl < 4; ++ntl) acc[mf][ntl] = (f32x4){0.f, 0.f, 0.f, 0.f};

#pragma unroll
  for (int kt = 0; kt < 8; ++kt) {
    short8x a[2];
#pragma unroll
    for (int mf = 0; mf < 2; ++mf) {
      int arow = mf * 16 + llo;
      a[mf] = *(const short8x*)(alds + arow * 512 +
                                ((kt * 64 + lhi * 16) ^ ((arow & 7) << 4)));
    }
#pragma unroll
    for (int ntl = 0; ntl < 4; ++ntl) {
      short8x b = *(const short8x*)(fp4 + (long)(kt * 16 + w * 4 + ntl) * 64 + l);
#pragma unroll
      for (int mf = 0; mf < 2; ++mf)
        acc[mf][ntl] = __builtin_amdgcn_mfma_f32_16x16x32_bf16(a[mf], b,
                                                               acc[mf][ntl], 0, 0, 0);
    }
  }

#pragma unroll
  for (int ntl = 0; ntl < 4; ++ntl) {
    int c = (w * 4 + ntl) * 16 + llo;
    float fb = fuseb[c];
#pragma unroll
    for (int mf = 0; mf < 2; ++mf)
#pragma unroll
      for (int r = 0; r < 4; ++r) {
        int p = mf * 16 + lhi * 4 + r;
        *(float*)(eb + swz32(p, c)) = acc[mf][ntl][r] + fb;
      }
  }
  __syncthreads();
  for (int i = tid; i < 8192; i += TPB) {
    int c = i >> 5, p = i & 31;
    long addr = (long)(n * 256 + c) * HWSZ + hw0 + p;
    out[addr] = x[addr] + *(const float*)(eb + swz32(p, c));
  }
}

// ---------------- ln2 + ff1 + GLU + ff2 + residual (out +=) ----------------
// M=64/block, 4 waves; per jc chunk: GEMM1 (wave = 4 nt = 2 GLU pair-blocks)
// -> in-reg GLU -> uC (LDS) -> GEMM2 partial (wave = 4 nt of N=256).
__global__ __launch_bounds__(TPB, 2) void k_ff(
    const float* __restrict__ xres, const float* __restrict__ mean2,
    const float* __restrict__ rstd2, const float* __restrict__ ln2w,
    const float* __restrict__ ln2b, const ushort_t* __restrict__ W1p,
    const float* __restrict__ ff1b, const ushort_t* __restrict__ W2p,
    const float* __restrict__ ff2b, float* __restrict__ out) {
  __shared__ __align__(16) char pool[49152];
  char* hA = pool;              // 64 x 512B bf16, swizzled; reused as f32 epilogue
  char* uC = pool + 32768;      // 64 x 256B bf16 (u chunk, 128 cols), swizzled

  int tid = threadIdx.x;
  int pix0 = blockIdx.x * 64;
  int n = pix0 / HWSZ, hw0 = pix0 % HWSZ;

  for (int i = tid; i < 16384; i += TPB) {
    int c = i >> 6, p = i & 63;
    int nc = n * 256 + c;
    float v = xres[(long)nc * HWSZ + hw0 + p];
    float hv = (v - mean2[nc]) * rstd2[nc] * ln2w[c] + ln2b[c];
    *(ushort_t*)(hA + p * 512 + ((c * 2) ^ ((p & 7) << 4))) = f2bf(hv);
  }
  __syncthreads();

  int l = tid & 63, w = tid >> 6;
  int llo = l & 15, lhi = l >> 4;

  const uint4* W1p4 = (const uint4*)W1p;
  const uint4* W2p4 = (const uint4*)W2p;

  f32x4 zacc[4][4];
#pragma unroll
  for (int mf = 0; mf < 4; ++mf)
#pragma unroll
    for (int ntl = 0; ntl < 4; ++ntl) zacc[mf][ntl] = (f32x4){0.f, 0.f, 0.f, 0.f};

  for (int jc = 0; jc < 4; ++jc) {
    // ---- GEMM1 chunk: wave w -> nt w*4..w*4+3 (pair-blocks w*2, w*2+1)
    f32x4 ca[4][4];
#pragma unroll
    for (int mf = 0; mf < 4; ++mf)
#pragma unroll
      for (int ntl = 0; ntl < 4; ++ntl) ca[mf][ntl] = (f32x4){0.f, 0.f, 0.f, 0.f};

#pragma unroll
    for (int kt = 0; kt < 8; ++kt) {
      short8x a[4];
#pragma unroll
      for (int mf = 0; mf < 4; ++mf) {
        int arow = mf * 16 + llo;
        a[mf] = *(const short8x*)(hA + arow * 512 +
                                  ((kt * 64 + lhi * 16) ^ ((llo & 7) << 4)));
      }
#pragma unroll
      for (int ntl = 0; ntl < 4; ++ntl) {
        short8x b = *(const short8x*)(W1p4 + (long)(((jc * 8 + kt) * 16) +
                                                    w * 4 + ntl) * 64 + l);
#pragma unroll
        for (int mf = 0; mf < 4; ++mf)
          ca[mf][ntl] = __builtin_amdgcn_mfma_f32_16x16x32_bf16(a[mf], b,
                                                                ca[mf][ntl], 0, 0, 0);
      }
    }

    // ---- GLU: pairs (ntl even = a, ntl odd = g) -> uC cols w*32..w*32+31
#pragma unroll
    for (int pb = 0; pb < 2; ++pb) {
      int cacol = jc * 128 + (w * 2 + pb) * 16 + llo;
      float ba = ff1b[cacol], bg = ff1b[512 + cacol];
      int cu = w * 32 + pb * 16 + llo;
#pragma unroll
      for (int mf = 0; mf < 4; ++mf)
#pragma unroll
        for (int r = 0; r < 4; ++r) {
          float av = ca[mf][2 * pb][r] + ba;
          float gv = ca[mf][2 * pb + 1][r] + bg;
          int p = mf * 16 + lhi * 4 + r;
          *(ushort_t*)(uC + p * 256 + ((cu * 2) ^ ((p & 7) << 4))) =
              f2bf(av * sigf(gv));
        }
    }
    __syncthreads();

    // ---- GEMM2 partial: K-chunk jc (4 kt2), wave w -> nt w*4..w*4+3
#pragma unroll
    for (int kt2 = 0; kt2 < 4; ++kt2) {
      short8x a2[4];
#pragma unroll
      for (int mf = 0; mf < 4; ++mf) {
        int arow = mf * 16 + llo;
        a2[mf] = *(const short8x*)(uC + arow * 256 +
                                   ((kt2 * 64 + lhi * 16) ^ ((llo & 7) << 4)));
      }
#pragma unroll
      for (int ntl = 0; ntl < 4; ++ntl) {
        short8x b = *(const short8x*)(W2p4 + (long)(((jc * 4 + kt2) * 16) +
                                                    w * 4 + ntl) * 64 + l);
#pragma unroll
        for (int mf = 0; mf < 4; ++mf)
          zacc[mf][ntl] = __builtin_amdgcn_mfma_f32_16x16x32_bf16(a2[mf], b,
                                                                  zacc[mf][ntl], 0, 0, 0);
      }
    }
    __syncthreads();
  }

  // ---- epilogue: 2 chunks of 32 rows, reuse hA as f32 swz32 buffer
  for (int q = 0; q < 2; ++q) {
#pragma unroll
    for (int mf = 0; mf < 4; ++mf) {
      if ((mf >> 1) != q) continue;
#pragma unroll
      for (int ntl = 0; ntl < 4; ++ntl) {
        int c = (w * 4 + ntl) * 16 + llo;
        float fb = ff2b[c];
#pragma unroll
        for (int r = 0; r < 4; ++r) {
          int p = (mf & 1) * 16 + lhi * 4 + r;
          *(float*)(hA + swz32(p, c)) = zacc[mf][ntl][r] + fb;
        }
      }
    }
    __syncthreads();
    for (int i = tid; i < 8192; i += TPB) {
      int c = i >> 5, p = i & 31;
      long addr = (long)(n * 256 + c) * HWSZ + hw0 + q * 32 + p;
      out[addr] += *(const float*)(hA + swz32(p, c));
    }
    __syncthreads();
  }
}

extern "C" void kernel_launch(void* const* d_in, const int* in_sizes, int n_in,
                              void* d_out, int out_size, void* d_ws, size_t ws_size,
                              hipStream_t stream) {
  (void)in_sizes; (void)n_in; (void)out_size; (void)ws_size;
  const float* x     = (const float*)d_in[0];
  const float* ln1w  = (const float*)d_in[1];
  const float* ln1b  = (const float*)d_in[2];
  const float* dww   = (const float*)d_in[3];
  const float* dwb   = (const float*)d_in[4];
  const float* lr_w  = (const float*)d_in[5];
  const float* lr_b  = (const float*)d_in[6];
  const float* lr_gw = (const float*)d_in[7];
  const float* lr_gb = (const float*)d_in[8];
  const float* rl_w  = (const float*)d_in[9];
  const float* rl_b  = (const float*)d_in[10];
  const float* rl_gw = (const float*)d_in[11];
  const float* rl_gb = (const float*)d_in[12];
  const float* tb_w  = (const float*)d_in[13];
  const float* tb_b  = (const float*)d_in[14];
  const float* tb_gw = (const float*)d_in[15];
  const float* tb_gb = (const float*)d_in[16];
  const float* bt_w  = (const float*)d_in[17];
  const float* bt_b  = (const float*)d_in[18];
  const float* bt_gw = (const float*)d_in[19];
  const float* bt_gb = (const float*)d_in[20];
  const float* fusew = (const float*)d_in[21];
  const float* fuseb = (const float*)d_in[22];
  const float* ln2w  = (const float*)d_in[23];
  const float* ln2b  = (const float*)d_in[24];
  const float* ff1w  = (const float*)d_in[25];
  const float* ff1b  = (const float*)d_in[26];
  const float* ff2w  = (const float*)d_in[27];
  const float* ff2b  = (const float*)d_in[28];

  float* out = (float*)d_out;
  ushort_t* y = (ushort_t*)d_ws;                  // 18874368 bf16
  ushort_t* o = y + 18874368;                     // 18874368 bf16
  float* mean1 = (float*)(o + 18874368);
  float* rstd1 = mean1 + 2048;
  float* mean2 = rstd1 + 2048;
  float* rstd2 = mean2 + 2048;
  ushort_t* Gp  = (ushort_t*)(rstd2 + 2048);      // 262144
  ushort_t* Ftp = Gp + 262144;                    // 65536
  ushort_t* W1p = Ftp + 65536;                    // 262144
  ushort_t* W2p = W1p + 262144;                   // 131072

  k_pack<<<2816, TPB, 0, stream>>>(lr_gw, rl_gw, tb_gw, bt_gw, fusew, ff1w, ff2w,
                                   Gp, Ftp, W1p, W2p);
  k_stats<<<2048, TPB, 0, stream>>>(x, mean1, rstd1);
  k_lndw<<<6144, TPB, 0, stream>>>(x, mean1, rstd1, ln1w, ln1b, dww, dwb, y);
  k_scan<0><<<2304, TPB, 0, stream>>>(y, Gp, lr_w, lr_b, lr_gb, rl_w, rl_b, rl_gb, o);
  k_scan<1><<<2304, TPB, 0, stream>>>(y, Gp, tb_w, tb_b, tb_gb, bt_w, bt_b, bt_gb, o);
  k_fuse<<<2304, TPB, 0, stream>>>(o, Ftp, fuseb, x, out);
  k_stats<<<2048, TPB, 0, stream>>>(out, mean2, rstd2);
  k_ff<<<1152, TPB, 0, stream>>>(out, mean2, rstd2, ln2w, ln2b, W1p, ff1b,
                                 W2p, ff2b, out);
}

// Round 5
// 446.823 us; speedup vs baseline: 2.0403x; 1.4172x over previous
//
#include <hip/hip_runtime.h>

#define TPB 256
#define HWSZ 9216      // 96*96

typedef __attribute__((ext_vector_type(8))) short short8x;
typedef __attribute__((ext_vector_type(4))) float f32x4;
typedef unsigned short ushort_t;
typedef unsigned int uint_t;

__device__ __forceinline__ float sigf(float v) { return 1.0f / (1.0f + __expf(-v)); }

__device__ __forceinline__ ushort_t f2bf(float f) {
  uint_t u = __float_as_uint(f);
  u = (u + 0x7fffu + ((u >> 16) & 1u)) >> 16;
  return (ushort_t)u;
}
__device__ __forceinline__ float bf2f(ushort_t h) {
  return __uint_as_float(((uint_t)h) << 16);
}

// fp32 epilogue-LDS swizzle (1024B rows): bijective, conflict-free columns
__device__ __forceinline__ int swz32(int p, int c) {
  return p * 1024 + ((((c * 4) ^ ((p & 7) << 4)) ^ (((p >> 3) & 3) << 2)));
}

// ---------------- pack weights to fragment-major bf16 ----------------
// B-frag tile(kt,nt): elem(l,j) = B[kt*32+(l>>4)*8+j][col(nt,l&15)], 1KB each
// Gp:  [dir4][kt8][nt16][64][8]
// Ftp: [kt8][nt16][64][8]
// W1p: [jc4][kt8][nt16][64][8], nt even: a-col jc*128+(nt>>1)*16+llo,
//                               nt odd : g-col 512+jc*128+(nt>>1)*16+llo
// W2p: [kt16][nt16][64][8]
__global__ __launch_bounds__(TPB) void k_pack(
    const float* __restrict__ lrg, const float* __restrict__ rlg,
    const float* __restrict__ tbg, const float* __restrict__ btg,
    const float* __restrict__ fusew, const float* __restrict__ ff1w,
    const float* __restrict__ ff2w,
    ushort_t* __restrict__ Gp, ushort_t* __restrict__ Ftp,
    ushort_t* __restrict__ W1p, ushort_t* __restrict__ W2p) {
  int i = blockIdx.x * TPB + threadIdx.x;
  if (i < 262144) {
    int d = i >> 16, r = i & 65535;
    int kt = r >> 13, nt = (r >> 9) & 15, l = (r >> 3) & 63, j = r & 7;
    int k = kt * 32 + (l >> 4) * 8 + j;
    int n_ = nt * 16 + (l & 15);
    const float* g = (d == 0) ? lrg : (d == 1) ? rlg : (d == 2) ? tbg : btg;
    Gp[i] = f2bf(g[n_ * 256 + k]);
  } else if (i < 327680) {
    int r = i - 262144;
    int kt = r >> 13, nt = (r >> 9) & 15, l = (r >> 3) & 63, j = r & 7;
    int k = kt * 32 + (l >> 4) * 8 + j;
    int n_ = nt * 16 + (l & 15);
    Ftp[r] = f2bf(fusew[n_ * 256 + k]);
  } else if (i < 589824) {
    int r = i - 327680;
    int jc = r >> 16, kt = (r >> 13) & 7, nt = (r >> 9) & 15, l = (r >> 3) & 63, j = r & 7;
    int k = kt * 32 + (l >> 4) * 8 + j;
    int base = jc * 128 + (nt >> 1) * 16 + (l & 15);
    int col = (nt & 1) ? (512 + base) : base;
    W1p[r] = f2bf(ff1w[col * 256 + k]);
  } else if (i < 720896) {
    int r = i - 589824;
    int kt = r >> 13, nt = (r >> 9) & 15, l = (r >> 3) & 63, j = r & 7;
    int k = kt * 32 + (l >> 4) * 8 + j;
    int n_ = nt * 16 + (l & 15);
    W2p[r] = f2bf(ff2w[n_ * 512 + k]);
  }
}

// ---------------- per-(n,c) LayerNorm2d stats ----------------
__global__ __launch_bounds__(TPB) void k_stats(const float* __restrict__ src,
                                               float* __restrict__ mean,
                                               float* __restrict__ rstd) {
  int nc = blockIdx.x;
  const float* p = src + (long)nc * HWSZ;
  float s = 0.f, s2 = 0.f;
  for (int i = threadIdx.x; i < HWSZ; i += TPB) {
    float v = p[i];
    s += v;
    s2 = fmaf(v, v, s2);
  }
#pragma unroll
  for (int off = 32; off > 0; off >>= 1) {
    s += __shfl_down(s, off);
    s2 += __shfl_down(s2, off);
  }
  __shared__ float ls[4], ls2[4];
  int lane = threadIdx.x & 63, wv = threadIdx.x >> 6;
  if (lane == 0) { ls[wv] = s; ls2[wv] = s2; }
  __syncthreads();
  if (threadIdx.x == 0) {
    float S = ls[0] + ls[1] + ls[2] + ls[3];
    float S2 = ls2[0] + ls2[1] + ls2[2] + ls2[3];
    float m = S * (1.0f / HWSZ);
    float var = S2 * (1.0f / HWSZ) - m * m;
    mean[nc] = m;
    rstd[nc] = rsqrtf(fmaxf(var, 0.f) + 1e-6f);
  }
}

// ---------------- ln1 + depthwise 3x3 -> y (NHWC bf16) ----------------
__global__ __launch_bounds__(TPB) void k_lndw(
    const float* __restrict__ x, const float* __restrict__ mean1,
    const float* __restrict__ rstd1, const float* __restrict__ ln1w,
    const float* __restrict__ ln1b, const float* __restrict__ dww,
    const float* __restrict__ dwb, ushort_t* __restrict__ y) {
  __shared__ float xl[3][32][101];
  int tid = threadIdx.x;
  int bid = blockIdx.x;
  int cb = (bid & 7) * 32;
  int h = (bid >> 3) % 96;
  int n = bid / 768;

  if (tid < 192) {
    int col = (tid & 1) ? 97 : 0;
    int rc = tid >> 1;
    xl[rc >> 5][rc & 31][col] = 0.f;
  }
  for (int i = tid; i < 3 * 32 * 96; i += TPB) {
    int w = i % 96;
    int rc = i / 96;
    int cc = rc & 31, rr = rc >> 5;
    int hh = h + rr - 1;
    float v = 0.f;
    if (hh >= 0 && hh < 96) {
      int c = cb + cc;
      int nc = n * 256 + c;
      float xv = x[(long)nc * HWSZ + hh * 96 + w];
      v = (xv - mean1[nc]) * rstd1[nc] * ln1w[c] + ln1b[c];
    }
    xl[rr][cc][w + 1] = v;
  }
  __syncthreads();

  int cc = tid & 31, wg = tid >> 5;
  int c = cb + cc;
  float wgt[9];
#pragma unroll
  for (int t = 0; t < 9; ++t) wgt[t] = dww[t * 256 + c];
  float bias = dwb[c];
  for (int wi = 0; wi < 12; ++wi) {
    int w = wg * 12 + wi;
    float acc = bias;
#pragma unroll
    for (int kh = 0; kh < 3; ++kh)
#pragma unroll
      for (int kw = 0; kw < 3; ++kw)
        acc = fmaf(xl[kh][cc][w + kw], wgt[kh * 3 + kw], acc);
    y[((long)(n * 96 + h) * 96 + w) * 256 + c] = f2bf(acc);
  }
}

// ---------------- scan pair: gate GEMM (B from L2) + dwconv1d*sigmoid --------
// Block = 32-pixel segment. 8 waves, wave w owns nt {w*2, w*2+1} (32 cols).
template <int VERT>
__global__ __launch_bounds__(512, 4) void k_scan(
    const ushort_t* __restrict__ y, const ushort_t* __restrict__ Gp,
    const float* __restrict__ dwaw, const float* __restrict__ dwab,
    const float* __restrict__ gab, const float* __restrict__ dwbw,
    const float* __restrict__ dwbb, const float* __restrict__ gbb,
    ushort_t* __restrict__ o) {
  __shared__ __align__(16) char pool[34816];
  char* ylds = pool;            // 36 rows x 512B, swizzled (pixel q at row q+2)
  char* olds = pool + 18432;    // 32 rows x 512B, swizzled

  int tid = threadIdx.x;
  int bid = blockIdx.x;
  int seg = bid % 3, line = (bid / 3) % 96, n = bid / 288;
  int p0 = seg * 32;

  for (int u = tid; u < 36 * 32; u += 512) {
    int r = u >> 5, ks = u & 31;
    int q = p0 - 2 + r;
    uint4 v = make_uint4(0, 0, 0, 0);
    if (q >= 0 && q < 96) {
      long pix = VERT ? ((long)(n * 96 + q) * 96 + line)
                      : ((long)(n * 96 + line) * 96 + q);
      v = *(const uint4*)(y + pix * 256 + ks * 8);
    }
    *(uint4*)(ylds + r * 512 + ((ks * 16) ^ ((r & 7) << 4))) = v;
  }
  __syncthreads();

  int l = tid & 63, w = tid >> 6;
  int llo = l & 15, lhi = l >> 4;

  const uint4* gp4 = (const uint4*)Gp;
  float part[2][2][4];

#pragma unroll
  for (int diri = 0; diri < 2; ++diri) {
    int dir = VERT * 2 + diri;
    f32x4 acc[2][2];
#pragma unroll
    for (int mf = 0; mf < 2; ++mf)
#pragma unroll
      for (int ntl = 0; ntl < 2; ++ntl) acc[mf][ntl] = (f32x4){0.f, 0.f, 0.f, 0.f};

#pragma unroll
    for (int kt = 0; kt < 8; ++kt) {
      short8x a[2];
#pragma unroll
      for (int mf = 0; mf < 2; ++mf) {
        int arow = 2 + mf * 16 + llo;
        a[mf] = *(const short8x*)(ylds + arow * 512 +
                                  ((kt * 64 + lhi * 16) ^ ((arow & 7) << 4)));
      }
#pragma unroll
      for (int ntl = 0; ntl < 2; ++ntl) {
        short8x b = *(const short8x*)(gp4 + (long)(((dir * 8 + kt) * 16) +
                                                   w * 2 + ntl) * 64 + l);
#pragma unroll
        for (int mf = 0; mf < 2; ++mf)
          acc[mf][ntl] = __builtin_amdgcn_mfma_f32_16x16x32_bf16(a[mf], b,
                                                                 acc[mf][ntl], 0, 0, 0);
      }
    }

    const float* dwv = diri ? dwbw : dwaw;
    const float* dbv = diri ? dwbb : dwab;
    const float* gbv = diri ? gbb : gab;
#pragma unroll
    for (int ntl = 0; ntl < 2; ++ntl) {
      int c = (w * 2 + ntl) * 16 + llo;
      float wt[5];
#pragma unroll
      for (int t = 0; t < 5; ++t)
        wt[t] = diri ? dwv[(4 - t) * 256 + c] : dwv[t * 256 + c];
      float cb = dbv[c], gb = gbv[c];
#pragma unroll
      for (int mf = 0; mf < 2; ++mf) {
        int pbase = mf * 16 + lhi * 4;
        float yv[8];
#pragma unroll
        for (int t = 0; t < 8; ++t) {
          int ry = pbase + t;
          yv[t] = bf2f(*(const ushort_t*)(ylds + ry * 512 +
                                          ((c * 2) ^ ((ry & 7) << 4))));
        }
#pragma unroll
        for (int r = 0; r < 4; ++r) {
          float conv = cb;
#pragma unroll
          for (int t = 0; t < 5; ++t) conv = fmaf(yv[r + t], wt[t], conv);
          float val = conv * sigf(acc[mf][ntl][r] + gb);
          if (diri == 0) {
            part[mf][ntl][r] = val;
          } else {
            int p = pbase + r;
            *(ushort_t*)(olds + p * 512 + ((c * 2) ^ ((p & 7) << 4))) =
                f2bf(part[mf][ntl][r] + val);
          }
        }
      }
    }
  }
  __syncthreads();

  for (int u = tid; u < 32 * 32; u += 512) {
    int p = u >> 5, ks = u & 31;
    uint4 v = *(const uint4*)(olds + p * 512 + ((ks * 16) ^ ((p & 7) << 4)));
    long pix = VERT ? ((long)(n * 96 + p0 + p) * 96 + line)
                    : ((long)(n * 96 + line) * 96 + p0 + p);
    ushort_t* dst = o + pix * 256 + ks * 8;
    if (VERT) {
      uint4 old = *(uint4*)dst;
      ushort_t* a8 = (ushort_t*)&v;
      ushort_t* b8 = (ushort_t*)&old;
#pragma unroll
      for (int j = 0; j < 8; ++j) a8[j] = f2bf(bf2f(a8[j]) + bf2f(b8[j]));
      *(uint4*)dst = v;
    } else {
      *(uint4*)dst = v;
    }
  }
}

// ---------------- fuse GEMM + residual: out(NCHW) = x + o@Ft + b ----------------
// 8 waves, wave w owns nt {w*2, w*2+1}.
__global__ __launch_bounds__(512, 4) void k_fuse(
    const ushort_t* __restrict__ o, const ushort_t* __restrict__ Ftp,
    const float* __restrict__ fuseb, const float* __restrict__ x,
    float* __restrict__ out) {
  __shared__ __align__(16) char pool[32768];
  char* alds = pool;            // 32 x 512B bf16, swizzled
  char* eb   = pool + 16384;    // 16 x 1024B f32, swz32 (per 16-row chunk)

  int tid = threadIdx.x;
  int pix0 = blockIdx.x * 32;
  int n = pix0 / HWSZ, hw0 = pix0 % HWSZ;

  for (int u = tid; u < 32 * 32; u += 512) {
    int r = u >> 5, ks = u & 31;
    uint4 v = *(const uint4*)(o + (long)(pix0 + r) * 256 + ks * 8);
    *(uint4*)(alds + r * 512 + ((ks * 16) ^ ((r & 7) << 4))) = v;
  }
  __syncthreads();

  int l = tid & 63, w = tid >> 6;
  int llo = l & 15, lhi = l >> 4;

  const uint4* fp4 = (const uint4*)Ftp;
  f32x4 acc[2][2];
#pragma unroll
  for (int mf = 0; mf < 2; ++mf)
#pragma unroll
    for (int ntl = 0; ntl < 2; ++ntl) acc[mf][ntl] = (f32x4){0.f, 0.f, 0.f, 0.f};

#pragma unroll
  for (int kt = 0; kt < 8; ++kt) {
    short8x a[2];
#pragma unroll
    for (int mf = 0; mf < 2; ++mf) {
      int arow = mf * 16 + llo;
      a[mf] = *(const short8x*)(alds + arow * 512 +
                                ((kt * 64 + lhi * 16) ^ ((arow & 7) << 4)));
    }
#pragma unroll
    for (int ntl = 0; ntl < 2; ++ntl) {
      short8x b = *(const short8x*)(fp4 + (long)(kt * 16 + w * 2 + ntl) * 64 + l);
#pragma unroll
      for (int mf = 0; mf < 2; ++mf)
        acc[mf][ntl] = __builtin_amdgcn_mfma_f32_16x16x32_bf16(a[mf], b,
                                                               acc[mf][ntl], 0, 0, 0);
    }
  }

  // epilogue: 2 chunks of 16 rows (chunk q = mf q)
  for (int q = 0; q < 2; ++q) {
    __syncthreads();  // WAR on eb / alds-read completion (q=0)
#pragma unroll
    for (int ntl = 0; ntl < 2; ++ntl) {
      int c = (w * 2 + ntl) * 16 + llo;
      float fb = fuseb[c];
#pragma unroll
      for (int r = 0; r < 4; ++r) {
        int p = lhi * 4 + r;
        *(float*)(eb + swz32(p, c)) = (q == 0 ? acc[0][ntl][r] : acc[1][ntl][r]) + fb;
      }
    }
    __syncthreads();
    for (int i = tid; i < 4096; i += 512) {
      int c = i >> 4, p = i & 15;
      long addr = (long)(n * 256 + c) * HWSZ + hw0 + q * 16 + p;
      out[addr] = x[addr] + *(const float*)(eb + swz32(p, c));
    }
  }
}

// ---------------- ln2 + ff1 + GLU + ff2 + residual (out +=) ----------------
// M=32/block, 8 waves; wave w = GLU pair-block w in GEMM1, nt {w*2,w*2+1} in GEMM2.
__global__ __launch_bounds__(512, 4) void k_ff(
    const float* __restrict__ xres, const float* __restrict__ mean2,
    const float* __restrict__ rstd2, const float* __restrict__ ln2w,
    const float* __restrict__ ln2b, const ushort_t* __restrict__ W1p,
    const float* __restrict__ ff1b, const ushort_t* __restrict__ W2p,
    const float* __restrict__ ff2b, float* __restrict__ out) {
  __shared__ __align__(16) char pool[32768];
  char* hA = pool;              // 32 x 512B bf16, swizzled
  char* uC = pool + 16384;      // 32 x 256B bf16, swizzled
  // epilogue reuses whole pool as 32 x 1024B f32 (swz32)

  int tid = threadIdx.x;
  int pix0 = blockIdx.x * 32;
  int n = pix0 / HWSZ, hw0 = pix0 % HWSZ;

  for (int i = tid; i < 8192; i += 512) {
    int c = i >> 5, p = i & 31;
    int nc = n * 256 + c;
    float v = xres[(long)nc * HWSZ + hw0 + p];
    float hv = (v - mean2[nc]) * rstd2[nc] * ln2w[c] + ln2b[c];
    *(ushort_t*)(hA + p * 512 + ((c * 2) ^ ((p & 7) << 4))) = f2bf(hv);
  }
  __syncthreads();

  int l = tid & 63, w = tid >> 6;
  int llo = l & 15, lhi = l >> 4;

  const uint4* W1p4 = (const uint4*)W1p;
  const uint4* W2p4 = (const uint4*)W2p;

  f32x4 zacc[2][2];
#pragma unroll
  for (int mf = 0; mf < 2; ++mf)
#pragma unroll
    for (int ntl = 0; ntl < 2; ++ntl) zacc[mf][ntl] = (f32x4){0.f, 0.f, 0.f, 0.f};

  for (int jc = 0; jc < 4; ++jc) {
    // ---- GEMM1 chunk: wave w -> pair-block w (nt w*2 = a, w*2+1 = g)
    f32x4 ca[2][2];
#pragma unroll
    for (int mf = 0; mf < 2; ++mf)
#pragma unroll
      for (int ntl = 0; ntl < 2; ++ntl) ca[mf][ntl] = (f32x4){0.f, 0.f, 0.f, 0.f};

#pragma unroll
    for (int kt = 0; kt < 8; ++kt) {
      short8x a[2];
#pragma unroll
      for (int mf = 0; mf < 2; ++mf) {
        int arow = mf * 16 + llo;
        a[mf] = *(const short8x*)(hA + arow * 512 +
                                  ((kt * 64 + lhi * 16) ^ ((llo & 7) << 4)));
      }
#pragma unroll
      for (int ntl = 0; ntl < 2; ++ntl) {
        short8x b = *(const short8x*)(W1p4 + (long)(((jc * 8 + kt) * 16) +
                                                    w * 2 + ntl) * 64 + l);
#pragma unroll
        for (int mf = 0; mf < 2; ++mf)
          ca[mf][ntl] = __builtin_amdgcn_mfma_f32_16x16x32_bf16(a[mf], b,
                                                                ca[mf][ntl], 0, 0, 0);
      }
    }

    // ---- GLU: pair-block w -> uC cols w*16..w*16+15
    {
      int cacol = jc * 128 + w * 16 + llo;
      float ba = ff1b[cacol], bg = ff1b[512 + cacol];
      int cu = w * 16 + llo;
#pragma unroll
      for (int mf = 0; mf < 2; ++mf)
#pragma unroll
        for (int r = 0; r < 4; ++r) {
          float av = ca[mf][0][r] + ba;
          float gv = ca[mf][1][r] + bg;
          int p = mf * 16 + lhi * 4 + r;
          *(ushort_t*)(uC + p * 256 + ((cu * 2) ^ ((p & 7) << 4))) =
              f2bf(av * sigf(gv));
        }
    }
    __syncthreads();

    // ---- GEMM2 partial: K-chunk jc (4 kt2), wave w -> nt {w*2, w*2+1}
#pragma unroll
    for (int kt2 = 0; kt2 < 4; ++kt2) {
      short8x a2[2];
#pragma unroll
      for (int mf = 0; mf < 2; ++mf) {
        int arow = mf * 16 + llo;
        a2[mf] = *(const short8x*)(uC + arow * 256 +
                                   ((kt2 * 64 + lhi * 16) ^ ((llo & 7) << 4)));
      }
#pragma unroll
      for (int ntl = 0; ntl < 2; ++ntl) {
        short8x b = *(const short8x*)(W2p4 + (long)(((jc * 4 + kt2) * 16) +
                                                    w * 2 + ntl) * 64 + l);
#pragma unroll
        for (int mf = 0; mf < 2; ++mf)
          zacc[mf][ntl] = __builtin_amdgcn_mfma_f32_16x16x32_bf16(a2[mf], b,
                                                                  zacc[mf][ntl], 0, 0, 0);
      }
    }
    __syncthreads();
  }

  // ---- epilogue: whole pool becomes 32 x 1024B f32 swz32 buffer
#pragma unroll
  for (int mf = 0; mf < 2; ++mf)
#pragma unroll
    for (int ntl = 0; ntl < 2; ++ntl) {
      int c = (w * 2 + ntl) * 16 + llo;
      float fb = ff2b[c];
#pragma unroll
      for (int r = 0; r < 4; ++r) {
        int p = mf * 16 + lhi * 4 + r;
        *(float*)(pool + swz32(p, c)) = zacc[mf][ntl][r] + fb;
      }
    }
  __syncthreads();
  for (int i = tid; i < 8192; i += 512) {
    int c = i >> 5, p = i & 31;
    long addr = (long)(n * 256 + c) * HWSZ + hw0 + p;
    out[addr] += *(const float*)(pool + swz32(p, c));
  }
}

extern "C" void kernel_launch(void* const* d_in, const int* in_sizes, int n_in,
                              void* d_out, int out_size, void* d_ws, size_t ws_size,
                              hipStream_t stream) {
  (void)in_sizes; (void)n_in; (void)out_size; (void)ws_size;
  const float* x     = (const float*)d_in[0];
  const float* ln1w  = (const float*)d_in[1];
  const float* ln1b  = (const float*)d_in[2];
  const float* dww   = (const float*)d_in[3];
  const float* dwb   = (const float*)d_in[4];
  const float* lr_w  = (const float*)d_in[5];
  const float* lr_b  = (const float*)d_in[6];
  const float* lr_gw = (const float*)d_in[7];
  const float* lr_gb = (const float*)d_in[8];
  const float* rl_w  = (const float*)d_in[9];
  const float* rl_b  = (const float*)d_in[10];
  const float* rl_gw = (const float*)d_in[11];
  const float* rl_gb = (const float*)d_in[12];
  const float* tb_w  = (const float*)d_in[13];
  const float* tb_b  = (const float*)d_in[14];
  const float* tb_gw = (const float*)d_in[15];
  const float* tb_gb = (const float*)d_in[16];
  const float* bt_w  = (const float*)d_in[17];
  const float* bt_b  = (const float*)d_in[18];
  const float* bt_gw = (const float*)d_in[19];
  const float* bt_gb = (const float*)d_in[20];
  const float* fusew = (const float*)d_in[21];
  const float* fuseb = (const float*)d_in[22];
  const float* ln2w  = (const float*)d_in[23];
  const float* ln2b  = (const float*)d_in[24];
  const float* ff1w  = (const float*)d_in[25];
  const float* ff1b  = (const float*)d_in[26];
  const float* ff2w  = (const float*)d_in[27];
  const float* ff2b  = (const float*)d_in[28];

  float* out = (float*)d_out;
  ushort_t* y = (ushort_t*)d_ws;                  // 18874368 bf16
  ushort_t* o = y + 18874368;                     // 18874368 bf16
  float* mean1 = (float*)(o + 18874368);
  float* rstd1 = mean1 + 2048;
  float* mean2 = rstd1 + 2048;
  float* rstd2 = mean2 + 2048;
  ushort_t* Gp  = (ushort_t*)(rstd2 + 2048);      // 262144
  ushort_t* Ftp = Gp + 262144;                    // 65536
  ushort_t* W1p = Ftp + 65536;                    // 262144
  ushort_t* W2p = W1p + 262144;                   // 131072

  k_pack<<<2816, TPB, 0, stream>>>(lr_gw, rl_gw, tb_gw, bt_gw, fusew, ff1w, ff2w,
                                   Gp, Ftp, W1p, W2p);
  k_stats<<<2048, TPB, 0, stream>>>(x, mean1, rstd1);
  k_lndw<<<6144, TPB, 0, stream>>>(x, mean1, rstd1, ln1w, ln1b, dww, dwb, y);
  k_scan<0><<<2304, 512, 0, stream>>>(y, Gp, lr_w, lr_b, lr_gb, rl_w, rl_b, rl_gb, o);
  k_scan<1><<<2304, 512, 0, stream>>>(y, Gp, tb_w, tb_b, tb_gb, bt_w, bt_b, bt_gb, o);
  k_fuse<<<2304, 512, 0, stream>>>(o, Ftp, fuseb, x, out);
  k_stats<<<2048, TPB, 0, stream>>>(out, mean2, rstd2);
  k_ff<<<2304, 512, 0, stream>>>(out, mean2, rstd2, ln2w, ln2b, W1p, ff1b,
                                 W2p, ff2b, out);
}